// Round 2
// baseline (90530.066 us; speedup 1.0000x reference)
//
#include <hip/hip_runtime.h>

// Farthest Point Sampling: points (B, N, 3) fp32 -> indices (B, M) int32.
// B=16, N=65536, M=2048.
//
// Round 2: full-fp64 trajectory. Hypothesis (from R1's absmax=22272 = one
// late tie-flip): the harness 'np' reference promotes inputs to float64.
// We mirror numpy-f64 semantics bit-exactly:
//   dx = (double)x - (double)cx            (promotion exact, f64 subtract)
//   d  = ((dx*dx + dy*dy) + dz*dz)         (separate rounding, no FMA)
//   min_dist = fmin(min_dist, d)           (f64 state)
//   argmax: first (lowest) index on ties   (np.argmax)
//
// State layout: min_dist is 65536 doubles/batch = 512 KB.
//   512 threads x 112 entries in VGPRs (224 VGPR; __launch_bounds__(512,2)
//   caps at 256) + 512 threads x 16 entries in static LDS (64 KB, under the
//   static-LDS limit). Thread t owns global indices t + j*512, j ascending,
//   so strict '>' keeps the first occurrence within a thread; cross-lane
//   reduction breaks ties by min index => global first-occurrence argmax.

#define N_PTS   65536
#define M_SAMP  2048
#define NT      512
#define RPT     112               // min-dist entries per thread in registers
#define LPT     16                // min-dist entries per thread in LDS
#define NWAVES  (NT / 64)         // 8

__global__ __launch_bounds__(NT, 2)
void fps_fp64(const float* __restrict__ pts, int* __restrict__ out) {
  const int b = blockIdx.x;
  const float* __restrict__ p = pts + (size_t)b * (size_t)(N_PTS * 3);
  int* __restrict__ o = out + (size_t)b * M_SAMP;
  const int t = threadIdx.x;

  __shared__ double s_md[LPT * NT];   // 65536 B
  __shared__ double s_bv[NWAVES];
  __shared__ int    s_bi[NWAVES];
  __shared__ int    s_widx;

  double md[RPT];
#pragma unroll
  for (int j = 0; j < RPT; ++j) md[j] = 1e10;
#pragma unroll
  for (int j = 0; j < LPT; ++j) s_md[j * NT + t] = 1e10;  // private slot, no race

  if (t == 0) o[0] = 0;
  int widx = 0;

  for (int m = 1; m < M_SAMP; ++m) {
    const double cx = (double)p[3 * widx + 0];
    const double cy = (double)p[3 * widx + 1];
    const double cz = (double)p[3 * widx + 2];

    double bestv = -1.0;   // d >= 0 always beats this
    int    besti = 0;

    // Register-resident portion: j = 0..RPT-1, global idx = t + j*NT (ascending)
#pragma unroll
    for (int j = 0; j < RPT; ++j) {
      const int idx = t + j * NT;
      const double dx = __dsub_rn((double)p[3 * idx + 0], cx);
      const double dy = __dsub_rn((double)p[3 * idx + 1], cy);
      const double dz = __dsub_rn((double)p[3 * idx + 2], cz);
      const double d  = __dadd_rn(__dadd_rn(__dmul_rn(dx, dx),
                                            __dmul_rn(dy, dy)),
                                  __dmul_rn(dz, dz));
      const double nmd = fmin(md[j], d);
      md[j] = nmd;
      if (nmd > bestv) { bestv = nmd; besti = idx; }
    }

    // LDS-resident portion: j = RPT..RPT+LPT-1 (still ascending indices)
#pragma unroll
    for (int j = 0; j < LPT; ++j) {
      const int idx = t + (RPT + j) * NT;
      const double dx = __dsub_rn((double)p[3 * idx + 0], cx);
      const double dy = __dsub_rn((double)p[3 * idx + 1], cy);
      const double dz = __dsub_rn((double)p[3 * idx + 2], cz);
      const double d  = __dadd_rn(__dadd_rn(__dmul_rn(dx, dx),
                                            __dmul_rn(dy, dy)),
                                  __dmul_rn(dz, dz));
      const double nmd = fmin(s_md[j * NT + t], d);
      s_md[j * NT + t] = nmd;
      if (nmd > bestv) { bestv = nmd; besti = idx; }
    }

    // 64-lane butterfly argmax, min-index tie-break.
#pragma unroll
    for (int off = 32; off >= 1; off >>= 1) {
      const double ov = __shfl_xor(bestv, off, 64);
      const int    oi = __shfl_xor(besti, off, 64);
      if (ov > bestv || (ov == bestv && oi < besti)) { bestv = ov; besti = oi; }
    }
    if ((t & 63) == 0) { s_bv[t >> 6] = bestv; s_bi[t >> 6] = besti; }
    __syncthreads();

    // Wave 0, lanes 0..NWAVES-1 reduce the per-wave winners.
    if (t < NWAVES) {
      bestv = s_bv[t];
      besti = s_bi[t];
#pragma unroll
      for (int off = NWAVES / 2; off >= 1; off >>= 1) {
        const double ov = __shfl_xor(bestv, off, 64);
        const int    oi = __shfl_xor(besti, off, 64);
        if (ov > bestv || (ov == bestv && oi < besti)) { bestv = ov; besti = oi; }
      }
      if (t == 0) { s_widx = besti; o[m] = besti; }
    }
    __syncthreads();
    widx = s_widx;
    // s_bv/s_bi/s_widx reuse is separated by the two barriers each loop:
    // next writes occur only after all threads pass the barrier following
    // the reads (verified in R1 structure).
  }
}

extern "C" void kernel_launch(void* const* d_in, const int* in_sizes, int n_in,
                              void* d_out, int out_size, void* d_ws, size_t ws_size,
                              hipStream_t stream) {
  const float* pts = (const float*)d_in[0];
  int* out = (int*)d_out;
  const int B = in_sizes[0] / (N_PTS * 3);   // 16
  hipLaunchKernelGGL(fps_fp64, dim3(B), dim3(NT), 0, stream, pts, out);
}

// Round 3
// 28325.980 us; speedup vs baseline: 3.1960x; 3.1960x over previous
//
#include <hip/hip_runtime.h>

// Farthest Point Sampling: points (B, N, 3) fp32 -> indices (B, M) int32.
// B=16, N=65536, M=2048.  Reference semantics (locked in R2, absmax=0):
// float64 pipeline: dx=(double)x-(double)cx; d=((dx*dx+dy*dy)+dz*dz) with
// separate rounding (no FMA); min via fmin; argmax first-index tie-break.
//
// Round 3: fix R2's scratch spill (md[112] -> HBM round-trip, 41+27 GB) and
// 16/256 CU usage. 16 blocks/batch x 16 batches = 256 blocks x 512 threads;
// md[8] per thread (16 VGPRs, SROA-promotable). Per-iteration cross-block
// sync via monotonic-counter spin barrier (agent-scope release/acquire),
// double-buffered (value,index) partials in d_ws:
//   - block writes its partial to buf[m&1], release-arrives on cnt[batch],
//     spins until cnt >= 16*m.
//   - buffer m&1 is next overwritten at m+2, which is after barrier m+1,
//     which is after all reads at m  => no race.
//   - all 16 blocks redundantly reduce the same 16 partials with identical
//     tie-break => identical widx everywhere (deterministic).
// Co-residency: 256 blocks <= 256 CUs, ~96 VGPR, ~100 B LDS -> all resident.

#define N_PTS   65536
#define M_SAMP  2048
#define NT      512
#define BPB     16                  // blocks per batch
#define PTS_BLK (N_PTS / BPB)       // 4096
#define PPT     (PTS_BLK / NT)      // 8 points per thread
#define NWAVES  (NT / 64)           // 8
#define NBATCH  16

// d_ws layout (bytes):
//   pv: unsigned long long [2][NBATCH][BPB]  @ 0      (4096 B)
//   pi: int                [2][NBATCH][BPB]  @ 4096   (2048 B)
//   cnt: int               [NBATCH]          @ 6144   (64 B)
#define WS_PV_OFF  0
#define WS_PI_OFF  4096
#define WS_CNT_OFF 6144

__global__ void fps_init_ws(int* __restrict__ cnt) {
  if (threadIdx.x < NBATCH) cnt[threadIdx.x] = 0;
}

__global__ __launch_bounds__(NT, 2)
void fps_multi(const float* __restrict__ pts, int* __restrict__ out,
               unsigned long long* __restrict__ pv, int* __restrict__ pi,
               int* __restrict__ cnt) {
  const int rank = blockIdx.x;                 // 0..BPB-1 within batch
  const int b    = blockIdx.y;                 // batch
  const float* __restrict__ p = pts + (size_t)b * (size_t)(N_PTS * 3);
  int* __restrict__ o = out + (size_t)b * M_SAMP;
  const int t = threadIdx.x;
  const int base = rank * PTS_BLK;

  __shared__ double s_bv[NWAVES];
  __shared__ int    s_bi[NWAVES];
  __shared__ int    s_widx;

  double md[PPT];
#pragma unroll
  for (int j = 0; j < PPT; ++j) md[j] = 1e10;

  if (rank == 0 && t == 0) o[0] = 0;
  int widx = 0;

  for (int m = 1; m < M_SAMP; ++m) {
    // Centroid coords: read-only array, plain loads are safe.
    const double cx = (double)p[3 * widx + 0];
    const double cy = (double)p[3 * widx + 1];
    const double cz = (double)p[3 * widx + 2];

    double bestv = -1.0;    // distances >= 0 always beat this
    int    besti = 0;

    // Thread t owns global indices base + t + j*NT, j ascending => strict '>'
    // keeps the first (lowest-index) maximum within a thread.
#pragma unroll
    for (int j = 0; j < PPT; ++j) {
      const int idx = base + t + j * NT;
      const double dx = __dsub_rn((double)p[3 * idx + 0], cx);
      const double dy = __dsub_rn((double)p[3 * idx + 1], cy);
      const double dz = __dsub_rn((double)p[3 * idx + 2], cz);
      const double d  = __dadd_rn(__dadd_rn(__dmul_rn(dx, dx),
                                            __dmul_rn(dy, dy)),
                                  __dmul_rn(dz, dz));
      const double nmd = fmin(md[j], d);
      md[j] = nmd;
      if (nmd > bestv) { bestv = nmd; besti = idx; }
    }

    // 64-lane butterfly argmax, min-index tie-break.
#pragma unroll
    for (int off = 32; off >= 1; off >>= 1) {
      const double ov = __shfl_xor(bestv, off, 64);
      const int    oi = __shfl_xor(besti, off, 64);
      if (ov > bestv || (ov == bestv && oi < besti)) { bestv = ov; besti = oi; }
    }
    if ((t & 63) == 0) { s_bv[t >> 6] = bestv; s_bi[t >> 6] = besti; }
    __syncthreads();

    // Wave 0 finishes the block reduction, does the cross-block exchange.
    if (t < 64) {
      if (t < NWAVES) {
        bestv = s_bv[t]; besti = s_bi[t];
#pragma unroll
        for (int off = NWAVES / 2; off >= 1; off >>= 1) {
          const double ov = __shfl_xor(bestv, off, 64);
          const int    oi = __shfl_xor(besti, off, 64);
          if (ov > bestv || (ov == bestv && oi < besti)) { bestv = ov; besti = oi; }
        }
      }
      const int buf = m & 1;
      const int grp = (buf * NBATCH + b) * BPB;
      if (t == 0) {
        // Publish block partial, arrive, spin until all BPB blocks arrived.
        __hip_atomic_store(&pv[grp + rank], __double_as_longlong(bestv),
                           __ATOMIC_RELAXED, __HIP_MEMORY_SCOPE_AGENT);
        __hip_atomic_store(&pi[grp + rank], besti,
                           __ATOMIC_RELAXED, __HIP_MEMORY_SCOPE_AGENT);
        __hip_atomic_fetch_add(&cnt[b], 1,
                               __ATOMIC_RELEASE, __HIP_MEMORY_SCOPE_AGENT);
        while (__hip_atomic_load(&cnt[b], __ATOMIC_ACQUIRE,
                                 __HIP_MEMORY_SCOPE_AGENT) < BPB * m)
          __builtin_amdgcn_s_sleep(1);
      }
      // Wave 0 reconverges only after lane 0's spin completes.
      if (t < BPB) {
        double v = __longlong_as_double(
            (long long)__hip_atomic_load(&pv[grp + t], __ATOMIC_RELAXED,
                                         __HIP_MEMORY_SCOPE_AGENT));
        int i = __hip_atomic_load(&pi[grp + t], __ATOMIC_RELAXED,
                                  __HIP_MEMORY_SCOPE_AGENT);
#pragma unroll
        for (int off = BPB / 2; off >= 1; off >>= 1) {
          const double ov = __shfl_xor(v, off, 64);
          const int    oi = __shfl_xor(i, off, 64);
          if (ov > v || (ov == v && oi < i)) { v = ov; i = oi; }
        }
        if (t == 0) {
          s_widx = i;
          if (rank == 0) o[m] = i;
        }
      }
    }
    __syncthreads();
    widx = s_widx;
  }
}

extern "C" void kernel_launch(void* const* d_in, const int* in_sizes, int n_in,
                              void* d_out, int out_size, void* d_ws, size_t ws_size,
                              hipStream_t stream) {
  const float* pts = (const float*)d_in[0];
  int* out = (int*)d_out;
  const int B = in_sizes[0] / (N_PTS * 3);   // 16

  char* ws = (char*)d_ws;
  unsigned long long* pv = (unsigned long long*)(ws + WS_PV_OFF);
  int* pi  = (int*)(ws + WS_PI_OFF);
  int* cnt = (int*)(ws + WS_CNT_OFF);

  // d_ws is re-poisoned to 0xAA before every launch: zero the counters.
  hipLaunchKernelGGL(fps_init_ws, dim3(1), dim3(64), 0, stream, cnt);
  hipLaunchKernelGGL(fps_multi, dim3(BPB, B), dim3(NT), 0, stream,
                     pts, out, pv, pi, cnt);
}

// Round 4
// 13518.488 us; speedup vs baseline: 6.6968x; 2.0954x over previous
//
#include <hip/hip_runtime.h>

// Farthest Point Sampling: points (B, N, 3) fp32 -> indices (B, M) int32.
// B=16, N=65536, M=2048.  Reference semantics (locked in R2, absmax=0):
// float64 pipeline: dx=(double)x-(double)cx; d=((dx*dx+dy*dy)+dz*dz) with
// separate rounding (no FMA); min via fmin; argmax first-index tie-break.
//
// Round 4: replace R3's contended fetch_add barrier (16 serialized cross-XCD
// RMWs on one line ~= 13 us/iter) with a store/poll flag barrier:
//   writer (lane 0):  pv[slot] = value_bits   (relaxed, agent)
//                     pt[slot] = (m<<32)|idx  (release, agent)
//   readers (t<16):   poll pt[grp+t] (acquire) until tag==m, then read pv.
// Plain stores don't serialize on line ownership; detection is one parallel
// coalesced load. Double buffer on m&1: slot written at m is rewritten at
// m+2, which happens only after the writer saw ALL tags m+1, which are
// posted only after every block finished reading buffer m  => no race.
// 0xAA workspace poison gives tag 0xAAAAAAAA != any m in [1,2048) => no
// init kernel, no false positives.
//
// Also: stage each block's 4096-pt slice into 48 KB LDS once. The acquire
// polls invalidate L1 every iteration; LDS is immune, and the stride-3-dword
// layout gives only 2-way bank aliasing (free on gfx950).

#define N_PTS   65536
#define M_SAMP  2048
#define NT      512
#define BPB     16                  // blocks per batch
#define PTS_BLK (N_PTS / BPB)       // 4096
#define PPT     (PTS_BLK / NT)      // 8 points per thread
#define NWAVES  (NT / 64)           // 8
#define NBATCH  16

typedef unsigned long long u64;

// d_ws layout (bytes):
//   pv: u64 [2][NBATCH][BPB] @ 0     (4096 B)  -- fp64 partial-max bits
//   pt: u64 [2][NBATCH][BPB] @ 4096  (4096 B)  -- (m<<32)|idx tag words
#define WS_PV_OFF 0
#define WS_PT_OFF 4096

__global__ __launch_bounds__(NT, 2)
void fps_multi(const float* __restrict__ pts, int* __restrict__ out,
               u64* __restrict__ pv, u64* __restrict__ pt) {
  const int rank = blockIdx.x;                 // 0..BPB-1 within batch
  const int b    = blockIdx.y;                 // batch
  const float* __restrict__ p = pts + (size_t)b * (size_t)(N_PTS * 3);
  int* __restrict__ o = out + (size_t)b * M_SAMP;
  const int t = threadIdx.x;
  const int base = rank * PTS_BLK;

  __shared__ float  s_pts[PTS_BLK * 3];        // 48 KB point slice
  __shared__ double s_bv[NWAVES];
  __shared__ int    s_bi[NWAVES];
  __shared__ int    s_widx;

  // One-time stage: global -> LDS, coalesced.
  for (int i = t; i < PTS_BLK * 3; i += NT)
    s_pts[i] = p[base * 3 + i];

  double md[PPT];
#pragma unroll
  for (int j = 0; j < PPT; ++j) md[j] = 1e10;

  if (rank == 0 && t == 0) o[0] = 0;
  int widx = 0;

  __syncthreads();   // staging complete

  for (int m = 1; m < M_SAMP; ++m) {
    // Centroid may lie outside this block's slice: read from global
    // (uniform address; L2 hit).
    const double cx = (double)p[3 * widx + 0];
    const double cy = (double)p[3 * widx + 1];
    const double cz = (double)p[3 * widx + 2];

    double bestv = -1.0;    // distances >= 0 always beat this
    int    besti = 0;

    // Thread t owns local indices t + j*NT (ascending) => strict '>'
    // keeps the first (lowest-index) maximum within a thread.
#pragma unroll
    for (int j = 0; j < PPT; ++j) {
      const int l = t + j * NT;                // local index in slice
      const double dx = __dsub_rn((double)s_pts[3 * l + 0], cx);
      const double dy = __dsub_rn((double)s_pts[3 * l + 1], cy);
      const double dz = __dsub_rn((double)s_pts[3 * l + 2], cz);
      const double d  = __dadd_rn(__dadd_rn(__dmul_rn(dx, dx),
                                            __dmul_rn(dy, dy)),
                                  __dmul_rn(dz, dz));
      const double nmd = fmin(md[j], d);
      md[j] = nmd;
      if (nmd > bestv) { bestv = nmd; besti = base + l; }
    }

    // 64-lane butterfly argmax, min-index tie-break.
#pragma unroll
    for (int off = 32; off >= 1; off >>= 1) {
      const double ov = __shfl_xor(bestv, off, 64);
      const int    oi = __shfl_xor(besti, off, 64);
      if (ov > bestv || (ov == bestv && oi < besti)) { bestv = ov; besti = oi; }
    }
    if ((t & 63) == 0) { s_bv[t >> 6] = bestv; s_bi[t >> 6] = besti; }
    __syncthreads();

    // Wave 0: finish block reduction, publish, poll, cross-block reduce.
    if (t < 64) {
      if (t < NWAVES) {
        bestv = s_bv[t]; besti = s_bi[t];
#pragma unroll
        for (int off = NWAVES / 2; off >= 1; off >>= 1) {
          const double ov = __shfl_xor(bestv, off, 64);
          const int    oi = __shfl_xor(besti, off, 64);
          if (ov > bestv || (ov == bestv && oi < besti)) { bestv = ov; besti = oi; }
        }
      }
      const int buf = m & 1;
      const int grp = (buf * NBATCH + b) * BPB;
      if (t == 0) {
        __hip_atomic_store(&pv[grp + rank], (u64)__double_as_longlong(bestv),
                           __ATOMIC_RELAXED, __HIP_MEMORY_SCOPE_AGENT);
        __hip_atomic_store(&pt[grp + rank],
                           ((u64)(unsigned)m << 32) | (u64)(unsigned)besti,
                           __ATOMIC_RELEASE, __HIP_MEMORY_SCOPE_AGENT);
      }
      if (t < BPB) {
        u64 w;
        for (;;) {
          w = __hip_atomic_load(&pt[grp + t], __ATOMIC_ACQUIRE,
                                __HIP_MEMORY_SCOPE_AGENT);
          if ((w >> 32) == (u64)(unsigned)m) break;
          __builtin_amdgcn_s_sleep(1);
        }
        double v = __longlong_as_double(
            (long long)__hip_atomic_load(&pv[grp + t], __ATOMIC_RELAXED,
                                         __HIP_MEMORY_SCOPE_AGENT));
        int i = (int)(w & 0xFFFFFFFFull);
#pragma unroll
        for (int off = BPB / 2; off >= 1; off >>= 1) {
          const double ov = __shfl_xor(v, off, 64);
          const int    oi = __shfl_xor(i, off, 64);
          if (ov > v || (ov == v && oi < i)) { v = ov; i = oi; }
        }
        if (t == 0) {
          s_widx = i;
          if (rank == 0) o[m] = i;
        }
      }
    }
    __syncthreads();
    widx = s_widx;
  }
}

extern "C" void kernel_launch(void* const* d_in, const int* in_sizes, int n_in,
                              void* d_out, int out_size, void* d_ws, size_t ws_size,
                              hipStream_t stream) {
  const float* pts = (const float*)d_in[0];
  int* out = (int*)d_out;
  const int B = in_sizes[0] / (N_PTS * 3);   // 16

  char* ws = (char*)d_ws;
  u64* pv = (u64*)(ws + WS_PV_OFF);
  u64* pt = (u64*)(ws + WS_PT_OFF);

  hipLaunchKernelGGL(fps_multi, dim3(BPB, B), dim3(NT), 0, stream,
                     pts, out, pv, pt);
}

// Round 5
// 10372.723 us; speedup vs baseline: 8.7277x; 1.3033x over previous
//
#include <hip/hip_runtime.h>

// Farthest Point Sampling: points (B, N, 3) fp32 -> indices (B, M) int32.
// B=16, N=65536, M=2048.  Reference semantics (locked in R2, absmax=0):
// float64 pipeline: dx=(double)x-(double)cx; d=((dx*dx+dy*dy)+dz*dz) with
// separate rounding (no FMA); min via fmin; argmax first-index tie-break.
//
// Round 5: R4's flag words shared cachelines -> 16 cross-XCD release stores
// serialized on line ownership (~6.6 us/iter). Fix: one 128-B cacheline per
// (buffer, batch, rank) slot:
//   slot[0] = (m<<32)|idx   (release-stored last)
//   slot[1] = fp64 value bits
//   slot[2] = (cy_bits<<32)|cx_bits   slot[3] = cz_bits
// Writers hit disjoint lines (parallel); readers poll 16 lines with one
// wave-parallel relaxed load, single acquire after detection. Winner coords
// ride in the slot so no global centroid read sits on the critical path.
// Double buffer on m&1 (slot rewritten at m+2 only after all blocks passed
// barrier m+1 => no race). 0xAA poison tag != any m in [1,2048) => no init.
// Points: pre-converted f64 in registers (48 VGPR; launch_bounds(512,2));
// LDS copy kept only for the once-per-iter winner-coord lookup.

#define N_PTS   65536
#define M_SAMP  2048
#define NT      512
#define BPB     16                  // blocks per batch
#define PTS_BLK (N_PTS / BPB)       // 4096
#define PPT     (PTS_BLK / NT)      // 8 points per thread
#define NWAVES  (NT / 64)           // 8
#define NBATCH  16
#define SLOT_U64 16                 // 128 B per slot

typedef unsigned long long u64;

__global__ __launch_bounds__(NT, 2)
void fps_multi(const float* __restrict__ pts, int* __restrict__ out,
               u64* __restrict__ ws) {
  const int rank = blockIdx.x;                 // 0..BPB-1 within batch
  const int b    = blockIdx.y;                 // batch
  const float* __restrict__ p = pts + (size_t)b * (size_t)(N_PTS * 3);
  int* __restrict__ o = out + (size_t)b * M_SAMP;
  const int t = threadIdx.x;
  const int base = rank * PTS_BLK;

  __shared__ float  s_pts[PTS_BLK * 3];        // 48 KB slice (winner lookup)
  __shared__ double s_bv[NWAVES];
  __shared__ int    s_bi[NWAVES];
  __shared__ float  s_c[3];                    // broadcast centroid coords

  // One-time stage: global -> LDS, coalesced.
  for (int i = t; i < PTS_BLK * 3; i += NT)
    s_pts[i] = p[base * 3 + i];

  if (rank == 0 && t == 0) o[0] = 0;
  if (t == 0) { s_c[0] = p[0]; s_c[1] = p[1]; s_c[2] = p[2]; }  // seed pt 0
  __syncthreads();

  // Own points pre-converted to f64 in registers; (double)x is exact.
  double pd[PPT][3];
  double md[PPT];
#pragma unroll
  for (int j = 0; j < PPT; ++j) {
    const int l = t + j * NT;
    pd[j][0] = (double)s_pts[3 * l + 0];
    pd[j][1] = (double)s_pts[3 * l + 1];
    pd[j][2] = (double)s_pts[3 * l + 2];
    md[j] = 1e10;
  }

  for (int m = 1; m < M_SAMP; ++m) {
    const double cx = (double)s_c[0];
    const double cy = (double)s_c[1];
    const double cz = (double)s_c[2];

    double bestv = -1.0;    // distances >= 0 always beat this
    int    besti = 0;

    // Thread t owns indices base + t + j*NT, j ascending => strict '>'
    // keeps the first (lowest-index) maximum within a thread.
#pragma unroll
    for (int j = 0; j < PPT; ++j) {
      const double dx = __dsub_rn(pd[j][0], cx);
      const double dy = __dsub_rn(pd[j][1], cy);
      const double dz = __dsub_rn(pd[j][2], cz);
      const double d  = __dadd_rn(__dadd_rn(__dmul_rn(dx, dx),
                                            __dmul_rn(dy, dy)),
                                  __dmul_rn(dz, dz));
      const double nmd = fmin(md[j], d);
      md[j] = nmd;
      if (nmd > bestv) { bestv = nmd; besti = base + t + j * NT; }
    }

    // 64-lane butterfly argmax, min-index tie-break.
#pragma unroll
    for (int off = 32; off >= 1; off >>= 1) {
      const double ov = __shfl_xor(bestv, off, 64);
      const int    oi = __shfl_xor(besti, off, 64);
      if (ov > bestv || (ov == bestv && oi < besti)) { bestv = ov; besti = oi; }
    }
    if ((t & 63) == 0) { s_bv[t >> 6] = bestv; s_bi[t >> 6] = besti; }
    __syncthreads();

    // Wave 0: finish block reduction, publish, poll, cross-block reduce.
    if (t < 64) {
      if (t < NWAVES) {
        bestv = s_bv[t]; besti = s_bi[t];
#pragma unroll
        for (int off = NWAVES / 2; off >= 1; off >>= 1) {
          const double ov = __shfl_xor(bestv, off, 64);
          const int    oi = __shfl_xor(besti, off, 64);
          if (ov > bestv || (ov == bestv && oi < besti)) { bestv = ov; besti = oi; }
        }
      }
      const u64 grp = (u64)(((m & 1) * NBATCH + b) * BPB);
      if (t == 0) {
        u64* slot = ws + (grp + rank) * SLOT_U64;
        const int l = besti - base;           // block winner is in our slice
        const unsigned wx = __float_as_uint(s_pts[3 * l + 0]);
        const unsigned wy = __float_as_uint(s_pts[3 * l + 1]);
        const unsigned wz = __float_as_uint(s_pts[3 * l + 2]);
        __hip_atomic_store(&slot[1], (u64)__double_as_longlong(bestv),
                           __ATOMIC_RELAXED, __HIP_MEMORY_SCOPE_AGENT);
        __hip_atomic_store(&slot[2], ((u64)wy << 32) | (u64)wx,
                           __ATOMIC_RELAXED, __HIP_MEMORY_SCOPE_AGENT);
        __hip_atomic_store(&slot[3], (u64)wz,
                           __ATOMIC_RELAXED, __HIP_MEMORY_SCOPE_AGENT);
        __hip_atomic_store(&slot[0],
                           ((u64)(unsigned)m << 32) | (u64)(unsigned)besti,
                           __ATOMIC_RELEASE, __HIP_MEMORY_SCOPE_AGENT);
      }
      if (t < BPB) {
        u64* rs = ws + (grp + t) * SLOT_U64;
        u64 w;
        do {
          w = __hip_atomic_load(&rs[0], __ATOMIC_RELAXED,
                                __HIP_MEMORY_SCOPE_AGENT);
        } while ((w >> 32) != (u64)(unsigned)m);
        // Order the data reads after the matching tag (same line anyway).
        (void)__hip_atomic_load(&rs[0], __ATOMIC_ACQUIRE,
                                __HIP_MEMORY_SCOPE_AGENT);
        double v = __longlong_as_double(
            (long long)__hip_atomic_load(&rs[1], __ATOMIC_RELAXED,
                                         __HIP_MEMORY_SCOPE_AGENT));
        const u64 cxy = __hip_atomic_load(&rs[2], __ATOMIC_RELAXED,
                                          __HIP_MEMORY_SCOPE_AGENT);
        const u64 czw = __hip_atomic_load(&rs[3], __ATOMIC_RELAXED,
                                          __HIP_MEMORY_SCOPE_AGENT);
        int i = (int)(w & 0xFFFFFFFFull);
        int r = t;                              // contributing rank
#pragma unroll
        for (int off = BPB / 2; off >= 1; off >>= 1) {
          const double ov = __shfl_xor(v, off, 64);
          const int    oi = __shfl_xor(i, off, 64);
          const int    orr = __shfl_xor(r, off, 64);
          if (ov > v || (ov == v && oi < i)) { v = ov; i = oi; r = orr; }
        }
        // All lanes 0..15 agree on winner rank r; fetch its coords by shuffle.
        float fx = __uint_as_float((unsigned)(cxy & 0xFFFFFFFFull));
        float fy = __uint_as_float((unsigned)(cxy >> 32));
        float fz = __uint_as_float((unsigned)(czw & 0xFFFFFFFFull));
        fx = __shfl(fx, r, 64);
        fy = __shfl(fy, r, 64);
        fz = __shfl(fz, r, 64);
        if (t == 0) {
          s_c[0] = fx; s_c[1] = fy; s_c[2] = fz;
          if (rank == 0) o[m] = i;
        }
      }
    }
    __syncthreads();
  }
}

extern "C" void kernel_launch(void* const* d_in, const int* in_sizes, int n_in,
                              void* d_out, int out_size, void* d_ws, size_t ws_size,
                              hipStream_t stream) {
  const float* pts = (const float*)d_in[0];
  int* out = (int*)d_out;
  const int B = in_sizes[0] / (N_PTS * 3);   // 16
  // ws usage: 2 * 16 * 16 slots * 128 B = 64 KB.
  hipLaunchKernelGGL(fps_multi, dim3(BPB, B), dim3(NT), 0, stream,
                     pts, out, (u64*)d_ws);
}

// Round 6
// 5836.462 us; speedup vs baseline: 15.5111x; 1.7772x over previous
//
#include <hip/hip_runtime.h>

// Farthest Point Sampling: points (B, N, 3) fp32 -> indices (B, M) int32.
// B=16, N=65536, M=2048.  Reference semantics (locked in R2, absmax=0):
// float64 pipeline: dx=(double)x-(double)cx; d=((dx*dx+dy*dy)+dz*dz) with
// separate rounding (no FMA); min via fmin; argmax first-index tie-break.
//
// Round 6: fence-free barrier. R5 burned ~2 fabric RTs on release (waitcnt
// for data-store acks before the tag store) and invalidated caches with
// acquire every iteration. Now the whole exchange is 4 self-tagged 8-B
// relaxed atomic words per (buffer, batch, rank) 128-B slot:
//   A = value_lo32<<32 | m<<16 | idx          (idx<65536, m<2048: 16b each)
//   B = value_hi32<<32 | m<<16 | idx
//   C = x_bits<<32     | m<<16 | y_hi16
//   D = y_lo16<<48     | z_bits<<16 | m
// Aligned 8-B stores are single-copy atomic; every word carries m, so any
// epoch mix tears are detected and re-polled. Writer: 4 relaxed stores, all
// in flight together (~1 RT). Reader: poll 4 relaxed loads until all tags
// == m; payload (value, idx, winner coords) arrives WITH the tags — no
// acquire, no second read, no global centroid fetch. Zero fences in the
// kernel => read-only points stay cached.
// Reuse safety (parity m&1): slot rewritten at m+2 only after its writer saw
// all tags m+1, which post only after every block finished reading m.
// 0xAA poison tag = 0xAAAA != any m in [1,2048) => no init kernel.

#define N_PTS   65536
#define M_SAMP  2048
#define NT      512
#define BPB     16                  // blocks per batch
#define PTS_BLK (N_PTS / BPB)       // 4096
#define PPT     (PTS_BLK / NT)      // 8 points per thread
#define NWAVES  (NT / 64)           // 8
#define NBATCH  16
#define SLOT_U64 16                 // 128 B per slot

typedef unsigned long long u64;

__device__ __forceinline__ u64 ld_agent(const u64* a) {
  return __hip_atomic_load(a, __ATOMIC_RELAXED, __HIP_MEMORY_SCOPE_AGENT);
}
__device__ __forceinline__ void st_agent(u64* a, u64 v) {
  __hip_atomic_store(a, v, __ATOMIC_RELAXED, __HIP_MEMORY_SCOPE_AGENT);
}

__global__ __launch_bounds__(NT, 2)
void fps_multi(const float* __restrict__ pts, int* __restrict__ out,
               u64* __restrict__ ws) {
  const int rank = blockIdx.x;                 // 0..BPB-1 within batch
  const int b    = blockIdx.y;                 // batch
  const float* __restrict__ p = pts + (size_t)b * (size_t)(N_PTS * 3);
  int* __restrict__ o = out + (size_t)b * M_SAMP;
  const int t = threadIdx.x;
  const int base = rank * PTS_BLK;

  __shared__ float  s_pts[PTS_BLK * 3];        // 48 KB slice
  __shared__ double s_bv[NWAVES];
  __shared__ int    s_bi[NWAVES];
  __shared__ float  s_c[3];                    // broadcast centroid coords

  for (int i = t; i < PTS_BLK * 3; i += NT)
    s_pts[i] = p[base * 3 + i];
  if (rank == 0 && t == 0) o[0] = 0;
  if (t == 0) { s_c[0] = p[0]; s_c[1] = p[1]; s_c[2] = p[2]; }  // seed pt 0
  __syncthreads();

  // Own points pre-converted to f64 in registers; (double)x is exact.
  double pd[PPT][3];
  double md[PPT];
#pragma unroll
  for (int j = 0; j < PPT; ++j) {
    const int l = t + j * NT;
    pd[j][0] = (double)s_pts[3 * l + 0];
    pd[j][1] = (double)s_pts[3 * l + 1];
    pd[j][2] = (double)s_pts[3 * l + 2];
    md[j] = 1e10;
  }

  for (int m = 1; m < M_SAMP; ++m) {
    const double cx = (double)s_c[0];
    const double cy = (double)s_c[1];
    const double cz = (double)s_c[2];

    double bestv = -1.0;    // distances >= 0 always beat this
    int    besti = 0;

    // Indices base + t + j*NT ascend with j => strict '>' keeps the first
    // (lowest-index) maximum within a thread.
#pragma unroll
    for (int j = 0; j < PPT; ++j) {
      const double dx = __dsub_rn(pd[j][0], cx);
      const double dy = __dsub_rn(pd[j][1], cy);
      const double dz = __dsub_rn(pd[j][2], cz);
      const double d  = __dadd_rn(__dadd_rn(__dmul_rn(dx, dx),
                                            __dmul_rn(dy, dy)),
                                  __dmul_rn(dz, dz));
      const double nmd = fmin(md[j], d);
      md[j] = nmd;
      if (nmd > bestv) { bestv = nmd; besti = base + t + j * NT; }
    }

    // 64-lane butterfly argmax, min-index tie-break.
#pragma unroll
    for (int off = 32; off >= 1; off >>= 1) {
      const double ov = __shfl_xor(bestv, off, 64);
      const int    oi = __shfl_xor(besti, off, 64);
      if (ov > bestv || (ov == bestv && oi < besti)) { bestv = ov; besti = oi; }
    }
    if ((t & 63) == 0) { s_bv[t >> 6] = bestv; s_bi[t >> 6] = besti; }
    __syncthreads();

    // Wave 0: finish block reduction, publish, poll, cross-block reduce.
    if (t < 64) {
      if (t < NWAVES) {
        bestv = s_bv[t]; besti = s_bi[t];
#pragma unroll
        for (int off = NWAVES / 2; off >= 1; off >>= 1) {
          const double ov = __shfl_xor(bestv, off, 64);
          const int    oi = __shfl_xor(besti, off, 64);
          if (ov > bestv || (ov == bestv && oi < besti)) { bestv = ov; besti = oi; }
        }
      }
      const u64 mm  = (u64)(unsigned)m;
      const u64 grp = (u64)(((m & 1) * NBATCH + b) * BPB);
      if (t == 0) {
        u64* slot = ws + (grp + rank) * SLOT_U64;
        const int l = besti - base;           // block winner is in our slice
        const unsigned xb = __float_as_uint(s_pts[3 * l + 0]);
        const unsigned yb = __float_as_uint(s_pts[3 * l + 1]);
        const unsigned zb = __float_as_uint(s_pts[3 * l + 2]);
        const u64 vb = (u64)__double_as_longlong(bestv);
        const u64 ti = (mm << 16) | (u64)(unsigned)besti;
        st_agent(&slot[0], (vb << 32) | ti);                          // A
        st_agent(&slot[1], (vb & 0xFFFFFFFF00000000ull) | ti);        // B
        st_agent(&slot[2], ((u64)xb << 32) | (mm << 16) | (u64)(yb >> 16));          // C
        st_agent(&slot[3], ((u64)(yb & 0xFFFFu) << 48) | ((u64)zb << 16) | mm);      // D
      }
      if (t < BPB) {
        const u64* rs = ws + (grp + t) * SLOT_U64;
        u64 A, B, C, D;
        for (;;) {
          A = ld_agent(rs + 0);
          B = ld_agent(rs + 1);
          C = ld_agent(rs + 2);
          D = ld_agent(rs + 3);
          const bool ok = (((A >> 16) & 0xFFFFull) == mm) &
                          (((B >> 16) & 0xFFFFull) == mm) &
                          (((C >> 16) & 0xFFFFull) == mm) &
                          ((D & 0xFFFFull) == mm);
          if (ok) break;
        }
        double v = __longlong_as_double(
            (long long)((B & 0xFFFFFFFF00000000ull) | (A >> 32)));
        int   i = (int)(A & 0xFFFFull);
        float fx = __uint_as_float((unsigned)(C >> 32));
        float fy = __uint_as_float((unsigned)(((C & 0xFFFFull) << 16) | (D >> 48)));
        float fz = __uint_as_float((unsigned)((D >> 16) & 0xFFFFFFFFull));
        int r = t;                              // contributing rank
#pragma unroll
        for (int off = BPB / 2; off >= 1; off >>= 1) {
          const double ov = __shfl_xor(v, off, 64);
          const int    oi = __shfl_xor(i, off, 64);
          const int    orr = __shfl_xor(r, off, 64);
          if (ov > v || (ov == v && oi < i)) { v = ov; i = oi; r = orr; }
        }
        // Lanes 0..15 agree on winner rank r; pull its coords by shuffle.
        fx = __shfl(fx, r, 64);
        fy = __shfl(fy, r, 64);
        fz = __shfl(fz, r, 64);
        if (t == 0) {
          s_c[0] = fx; s_c[1] = fy; s_c[2] = fz;
          if (rank == 0) o[m] = i;
        }
      }
    }
    __syncthreads();
  }
}

extern "C" void kernel_launch(void* const* d_in, const int* in_sizes, int n_in,
                              void* d_out, int out_size, void* d_ws, size_t ws_size,
                              hipStream_t stream) {
  const float* pts = (const float*)d_in[0];
  int* out = (int*)d_out;
  const int B = in_sizes[0] / (N_PTS * 3);   // 16
  // ws usage: 2 * 16 * 16 slots * 128 B = 64 KB.
  hipLaunchKernelGGL(fps_multi, dim3(BPB, B), dim3(NT), 0, stream,
                     pts, out, (u64*)d_ws);
}